// Round 1
// baseline (631.447 us; speedup 1.0000x reference)
//
#include <hip/hip_runtime.h>

typedef __bf16 bf16x8 __attribute__((ext_vector_type(8)));
typedef unsigned short u16x8 __attribute__((ext_vector_type(8)));
typedef float f32x4 __attribute__((ext_vector_type(4)));

#define MFMA(a, b, c) __builtin_amdgcn_mfma_f32_16x16x32_bf16(a, b, c, 0, 0, 0)

constexpr int L = 1024;
constexpr int D = 64;
constexpr int QT = 16;                       // q rows per workgroup
constexpr size_t OUT_ELEMS = 8ull * 16 * 1024 * 64;  // out tensor elements

__device__ __forceinline__ unsigned short f2bf(float x) {
    unsigned int u = __float_as_uint(x);
    u = u + 0x7FFFu + ((u >> 16) & 1u);      // round-to-nearest-even
    return (unsigned short)(u >> 16);
}
__device__ __forceinline__ float bf2f(unsigned short h) {
    return __uint_as_float(((unsigned int)h) << 16);
}
// element-space XOR swizzle: permutes 16B blocks within a row (bits 2-4 of col)
__device__ __forceinline__ int swz(int row, int col) {
    return row * L + (col ^ ((row & 7) << 2));
}

__device__ __forceinline__ void load_split8(const float* src, bf16x8& hi, bf16x8& lo) {
    float4 a0 = *(const float4*)(src);
    float4 a1 = *(const float4*)(src + 4);
    float xs[8] = {a0.x, a0.y, a0.z, a0.w, a1.x, a1.y, a1.z, a1.w};
    u16x8 hb, lb;
#pragma unroll
    for (int j = 0; j < 8; ++j) {
        unsigned short h = f2bf(xs[j]);
        hb[j] = h;
        lb[j] = f2bf(xs[j] - bf2f(h));
    }
    hi = __builtin_bit_cast(bf16x8, hb);
    lo = __builtin_bit_cast(bf16x8, lb);
}

__global__ __launch_bounds__(256, 2)
void attn_fused(const float* __restrict__ qg, const float* __restrict__ kg,
                const float* __restrict__ vg, const float* __restrict__ biasg,
                const int* __restrict__ maskg, float* __restrict__ outg) {
    __shared__ unsigned int lds[QT * L];     // 64 KiB: S (f32) then P packed {hi,lo} bf16

    const int wg = blockIdx.x;
    const int bh = wg >> 6;                  // 0..127  (b*16 + h)
    const int qt = wg & 63;
    const int b  = bh >> 4;
    const int q0 = qt * QT;
    const int tid  = threadIdx.x;
    const int wave = tid >> 6;
    const int lane = tid & 63;
    const int lg   = lane >> 4;              // 0..3
    const int lr   = lane & 15;              // 0..15

    const float* qp = qg + (size_t)bh * L * D;
    const float* kp = kg + (size_t)bh * L * D;
    const float* vp = vg + (size_t)bh * L * D;

    // ---- Q fragments (hi/lo split); A-frag: row = lane&15, k = (lane>>4)*8 + j ----
    bf16x8 qhi[2], qlo[2];
#pragma unroll
    for (int s = 0; s < 2; ++s) {
        load_split8(qp + (size_t)(q0 + lr) * D + s * 32 + lg * 8, qhi[s], qlo[s]);
    }

    // ---- QK^T -> LDS (raw dot products, fp32) ----
    const int cbase = wave * 256;
#pragma unroll 2
    for (int ct = 0; ct < 16; ++ct) {
        const int cb = cbase + ct * 16;
        f32x4 acc = {0.f, 0.f, 0.f, 0.f};
#pragma unroll
        for (int s = 0; s < 2; ++s) {
            bf16x8 khi, klo;
            // B-frag: col(key) = lane&15, k = (lane>>4)*8 + j  (8 consecutive d)
            load_split8(kp + (size_t)(cb + lr) * D + s * 32 + lg * 8, khi, klo);
            acc = MFMA(qhi[s], khi, acc);
            acc = MFMA(qlo[s], khi, acc);
            acc = MFMA(qhi[s], klo, acc);
        }
        // D-frag: col = lane&15, row = (lane>>4)*4 + r
#pragma unroll
        for (int r = 0; r < 4; ++r) {
            lds[swz(lg * 4 + r, cb + lr)] = __float_as_uint(acc[r]);
        }
    }
    __syncthreads();

    // ---- softmax: wave w owns rows 4w..4w+3; scale*bias, mask, write score ----
    const float* bbase = biasg + (size_t)b * L * L;
    const int*   mbase = maskg + (size_t)b * L * L;
    float* score = outg + OUT_ELEMS + (size_t)bh * L * L;
#pragma unroll
    for (int rr = 0; rr < 4; ++rr) {
        const int row  = wave * 4 + rr;
        const int grow = q0 + row;
        const float* brow = bbase + (size_t)grow * L;
        const int*   mrow = mbase + (size_t)grow * L;
        float sv[16];
        float mx = -3.0e38f;
#pragma unroll
        for (int i = 0; i < 16; ++i) {
            const int c = lane + 64 * i;
            float s = __uint_as_float(lds[swz(row, c)]);
            s = s * 0.125f * brow[c];
            if (mrow[c] == 0) s = -10000.0f;
            sv[i] = s;
            mx = fmaxf(mx, s);
        }
#pragma unroll
        for (int off = 32; off; off >>= 1) mx = fmaxf(mx, __shfl_xor(mx, off));
        float sum = 0.f;
#pragma unroll
        for (int i = 0; i < 16; ++i) { sv[i] = __expf(sv[i] - mx); sum += sv[i]; }
#pragma unroll
        for (int off = 32; off; off >>= 1) sum += __shfl_xor(sum, off);
        const float rinv = 1.0f / sum;
        float* srow = score + (size_t)grow * L;
#pragma unroll
        for (int i = 0; i < 16; ++i) {
            const int c = lane + 64 * i;
            const float p = sv[i] * rinv;
            srow[c] = p;                                   // coalesced 256B/instr
            unsigned short ph = f2bf(p);
            unsigned short pl = f2bf(p - bf2f(ph));
            lds[swz(row, c)] = ((unsigned int)pl << 16) | ph;   // in-place, same slot
        }
    }
    __syncthreads();

    // ---- PV: wave w owns d columns [16w,16w+16); contract all 1024 keys ----
    const int d0 = wave * 16;
    f32x4 oacc = {0.f, 0.f, 0.f, 0.f};
#pragma unroll 2
    for (int kb = 0; kb < L; kb += 32) {
        const int e0 = kb + lg * 8;
        // A-frag of P: row(q) = lane&15, k = e0 + j  (8 packed {hi,lo} uints)
        uint4 ua = *(const uint4*)&lds[swz(lr, e0)];
        uint4 ub = *(const uint4*)&lds[swz(lr, e0 + 4)];
        unsigned int uu[8] = {ua.x, ua.y, ua.z, ua.w, ub.x, ub.y, ub.z, ub.w};
        u16x8 hb, lb;
#pragma unroll
        for (int j = 0; j < 8; ++j) {
            hb[j] = (unsigned short)(uu[j] & 0xFFFFu);
            lb[j] = (unsigned short)(uu[j] >> 16);
        }
        bf16x8 phi = __builtin_bit_cast(bf16x8, hb);
        bf16x8 plo = __builtin_bit_cast(bf16x8, lb);
        // B-frag of V: col(d) = lane&15, k = e0 + j  (strided gather, L2-resident)
        u16x8 vh, vl;
#pragma unroll
        for (int j = 0; j < 8; ++j) {
            float x = vp[(size_t)(e0 + j) * D + d0 + lr];
            unsigned short h = f2bf(x);
            vh[j] = h;
            vl[j] = f2bf(x - bf2f(h));
        }
        bf16x8 vhi = __builtin_bit_cast(bf16x8, vh);
        bf16x8 vlo = __builtin_bit_cast(bf16x8, vl);
        oacc = MFMA(phi, vhi, oacc);
        oacc = MFMA(plo, vhi, oacc);
        oacc = MFMA(phi, vlo, oacc);
    }
#pragma unroll
    for (int r = 0; r < 4; ++r) {
        outg[((size_t)bh * L + q0 + lg * 4 + r) * D + d0 + lr] = oacc[r];
    }
}

extern "C" void kernel_launch(void* const* d_in, const int* in_sizes, int n_in,
                              void* d_out, int out_size, void* d_ws, size_t ws_size,
                              hipStream_t stream) {
    const float* q    = (const float*)d_in[0];
    const float* k    = (const float*)d_in[1];
    const float* v    = (const float*)d_in[2];
    const float* bias = (const float*)d_in[3];
    const int*   mask = (const int*)d_in[4];
    float* out = (float*)d_out;

    dim3 grid(8 * 16 * (L / QT));            // 8192 workgroups
    dim3 block(256);
    hipLaunchKernelGGL(attn_fused, grid, block, 0, stream, q, k, v, bias, mask, out);
}